// Round 2
// baseline (148.421 us; speedup 1.0000x reference)
//
#include <hip/hip_runtime.h>
#include <hip/hip_bf16.h>
#include <math.h>

// Problem constants (from reference): B=64, R=20, L=1024, D=2048, fp32.
#define BATCH 64
#define NREG  20
#define LWORDS 1024
#define DDIM  2048
#define DK    512          // D-chunk staged in LDS: 20*512*4B = 40 KB
#define WPW   4            // words per wave
#define TPB   256          // 4 waves per block
#define WORDS_PER_BLOCK (4 * WPW)   // 16

// DPP-based full-wave (64 lane) sum; result valid in lane 63 only.
// Classic GCN sequence: row_shr 1/2/4/8 then row_bcast15, row_bcast31.
template <int CTRL>
__device__ __forceinline__ float dpp_add_f32(float v) {
    int s = __builtin_amdgcn_update_dpp(0, __float_as_int(v), CTRL, 0xf, 0xf, true);
    return v + __int_as_float(s);
}

__device__ __forceinline__ float wave_sum64(float v) {
    v = dpp_add_f32<0x111>(v);  // row_shr:1
    v = dpp_add_f32<0x112>(v);  // row_shr:2
    v = dpp_add_f32<0x114>(v);  // row_shr:4
    v = dpp_add_f32<0x118>(v);  // row_shr:8  -> lane 16k+15 holds row sum
    v = dpp_add_f32<0x142>(v);  // row_bcast:15
    v = dpp_add_f32<0x143>(v);  // row_bcast:31 -> lane 63 holds total
    return v;
}

__global__ __launch_bounds__(TPB)
void score_max_kernel(const float* __restrict__ in0,   // (B*20, D) regions
                      const float* __restrict__ in1,   // (B, L, D) words
                      float* __restrict__ out) {       // (B, 1, L)
    __shared__ float reg_lds[NREG * DK];               // 40 KB

    const int bid  = blockIdx.x;
    // bid = t*64 + b : consecutive blocks are consecutive batches ->
    // batch b always lands on XCD (b % 8): regions stay L2-resident per XCD.
    const int b    = bid & 63;
    const int t    = bid >> 6;                          // word tile 0..63
    const int tid  = threadIdx.x;
    const int wave = tid >> 6;
    const int lane = tid & 63;
    const int l0   = t * WORDS_PER_BLOCK + wave * WPW;  // first word of this wave

    const float* regbase  = in0 + (size_t)b * NREG * DDIM;
    const float* wordbase = in1 + ((size_t)b * LWORDS + l0) * DDIM;

    float acc[NREG][WPW];
    #pragma unroll
    for (int r = 0; r < NREG; ++r)
        #pragma unroll
        for (int w = 0; w < WPW; ++w) acc[r][w] = 0.0f;

    for (int d0 = 0; d0 < DDIM; d0 += DK) {
        __syncthreads();   // protect LDS from previous chunk's readers
        // ---- stage regions[0..19][d0..d0+DK) into LDS, coalesced float4 ----
        #pragma unroll
        for (int i = 0; i < (NREG * DK / 4) / TPB; ++i) {   // 10 iters
            const int flat4 = i * TPB + tid;                 // 0..2559
            const int r  = flat4 >> 7;                        // /128 float4 per row
            const int c4 = flat4 & 127;
            const float4 v = *reinterpret_cast<const float4*>(
                regbase + (size_t)r * DDIM + d0 + c4 * 4);
            *reinterpret_cast<float4*>(&reg_lds[r * DK + c4 * 4]) = v;
        }
        __syncthreads();

        // ---- compute: each lane covers 4 floats, 2 passes over DK ----
        #pragma unroll
        for (int sub = 0; sub < DK; sub += 256) {
            float4 wv[WPW];
            #pragma unroll
            for (int w = 0; w < WPW; ++w)
                wv[w] = *reinterpret_cast<const float4*>(
                    wordbase + (size_t)w * DDIM + d0 + sub + lane * 4);
            #pragma unroll
            for (int r = 0; r < NREG; ++r) {
                const float4 rv = *reinterpret_cast<const float4*>(
                    &reg_lds[r * DK + sub + lane * 4]);
                #pragma unroll
                for (int w = 0; w < WPW; ++w) {
                    float a = acc[r][w];
                    a = fmaf(rv.x, wv[w].x, a);
                    a = fmaf(rv.y, wv[w].y, a);
                    a = fmaf(rv.z, wv[w].z, a);
                    a = fmaf(rv.w, wv[w].w, a);
                    acc[r][w] = a;
                }
            }
        }
    }

    // ---- epilogue: wave-sum each acc on the VALU pipe, max over regions ----
    #pragma unroll
    for (int w = 0; w < WPW; ++w) {
        float m = -INFINITY;
        #pragma unroll
        for (int r = 0; r < NREG; ++r) {
            const float s = wave_sum64(acc[r][w]);   // valid in lane 63
            m = fmaxf(m, s);
        }
        if (lane == 63) out[(size_t)b * LWORDS + l0 + w] = m;
    }
}

extern "C" void kernel_launch(void* const* d_in, const int* in_sizes, int n_in,
                              void* d_out, int out_size, void* d_ws, size_t ws_size,
                              hipStream_t stream) {
    const float* in0 = (const float*)d_in[0];   // (B*20, D)
    const float* in1 = (const float*)d_in[1];   // (B, L, D)
    float* out = (float*)d_out;                  // (B, 1, L) = 65536 floats

    const int grid = BATCH * (LWORDS / WORDS_PER_BLOCK);   // 64 * 64 = 4096
    score_max_kernel<<<grid, TPB, 0, stream>>>(in0, in1, out);
}